// Round 10
// baseline (110.894 us; speedup 1.0000x reference)
//
#include <hip/hip_runtime.h>

#define D 256
#define H 8
#define B 32
#define S 1024
#define SCH 16      // s-chunks per batch
#define SCS 64      // s per chunk  (best-measured stage-1 geometry)

// workspace layout (float offsets)
#define OFF_QK   0          // [H][D]                 2048
#define OFF_ML   2048       // [B][H][SCH] float2     8192 floats
#define OFF_XWP  10240      // [B][H][SCH][D]         1048576 floats (4 MB)

// ---- qk[h][k] = Wk[k, h*D+:] . q[h];  out = bo init. (R8-verified body)
__global__ void __launch_bounds__(256) k_prep(
        const float* __restrict__ Wk, const float* __restrict__ query,
        const float* __restrict__ bo, float* __restrict__ qk,
        float* __restrict__ out) {
    const int h  = blockIdx.x >> 5;
    const int kc = blockIdx.x & 31;
    const int t  = threadIdx.x;
    const int kl = t >> 5;
    const int dq = t & 31;
    const int k  = kc * 8 + kl;
    const int d0 = dq * 8;
    const float* wrow = Wk + (size_t)k * (D * H) + h * D + d0;
    const float* qrow = query + h * D + d0;
    const float4 w0 = *(const float4*)(wrow);
    const float4 w1 = *(const float4*)(wrow + 4);
    const float4 q0 = *(const float4*)(qrow);
    const float4 q1 = *(const float4*)(qrow + 4);
    float acc = w0.x * q0.x + w0.y * q0.y + w0.z * q0.z + w0.w * q0.w
              + w1.x * q1.x + w1.y * q1.y + w1.z * q1.z + w1.w * q1.w;
    #pragma unroll
    for (int msk = 1; msk < 32; msk <<= 1) acc += __shfl_xor(acc, msk);
    if (dq == 0) qk[h * D + k] = acc;
    if (h == 0) out[(size_t)kc * D + t] = bo[t];
}

// ---- One (b, chunk of 64 s), 512 threads (16 waves/CU at 512 blocks).
// Pass A: (sl = t>>3) x (dq = t&7), rotated-j conflict-free qkL reads
// (R4-verified geometry). Softmax: one wave per head. Pass B: s-range split
// across thread halves, x prefetched to regs before softmax, halves combined
// through the dead qkL region.
__global__ void __launch_bounds__(512, 2) k_fused(
        const float* __restrict__ x, const float* __restrict__ qk,
        float* __restrict__ xwp, float2* __restrict__ mlbuf) {
    const int b  = blockIdx.x >> 4;
    const int c  = blockIdx.x & 15;
    const int s0 = c * SCS;
    const int t  = threadIdx.x;
    __shared__ float qkL[H * D];            // 8 KB; pass-B staging overlays
    __shared__ float sc[SCS][H];            // 2 KB
    ((float4*)qkL)[t] = ((const float4*)qk)[t];   // 512 float4 = 2048 floats
    __syncthreads();

    // pass A
    {
        const int sl = t >> 3;
        const int dq = t & 7;
        const int d0 = dq * 32;
        const float* xrow = x + ((size_t)(b * S + s0 + sl)) * D + d0;
        float4 xr[8];
        #pragma unroll
        for (int j0 = 0; j0 < 8; j0++) {
            const int je = (j0 + dq) & 7;
            xr[j0] = *(const float4*)(xrow + je * 4);
        }
        float accA[H];
        #pragma unroll
        for (int hh = 0; hh < H; hh++) {
            const float* qb = &qkL[hh * D + d0];
            float a = 0.f;
            #pragma unroll
            for (int j0 = 0; j0 < 8; j0++) {
                const int je = (j0 + dq) & 7;
                const float4 qv = *(const float4*)(qb + je * 4);
                a += xr[j0].x * qv.x + xr[j0].y * qv.y
                   + xr[j0].z * qv.z + xr[j0].w * qv.w;
            }
            accA[hh] = a;
        }
        #pragma unroll
        for (int hh = 0; hh < H; hh++) {
            accA[hh] += __shfl_xor(accA[hh], 1);
            accA[hh] += __shfl_xor(accA[hh], 2);
            accA[hh] += __shfl_xor(accA[hh], 4);
        }
        if (dq == 0) {
            #pragma unroll
            for (int hh = 0; hh < H; hh++) sc[sl][hh] = accA[hh];
        }
    }

    // prefetch this thread's pass-B x half-column (32 loads) into registers:
    // they stay in flight across the softmax phase and its barriers.
    const int tt = t & 255;                 // d
    const int sh = t >> 8;                  // s-half (wave-uniform)
    float xv[32];
    {
        const float* xp = x + ((size_t)(b * S + s0 + sh * 32)) * D + tt;
        #pragma unroll
        for (int s = 0; s < 32; s++) xv[s] = xp[(size_t)s * D];
    }
    __syncthreads();

    // chunk softmax: one 64-lane wave per head (hh = t>>6, u = t&63 = s)
    {
        const int hh = t >> 6;
        const int u  = t & 63;
        const float v = sc[u][hh];
        float m = v;
        #pragma unroll
        for (int msk = 1; msk < 64; msk <<= 1) m = fmaxf(m, __shfl_xor(m, msk));
        const float e = __expf(v - m);
        float sum = e;
        #pragma unroll
        for (int msk = 1; msk < 64; msk <<= 1) sum += __shfl_xor(sum, msk);
        sc[u][hh] = e;
        if (u == 0) mlbuf[((size_t)(b * H + hh)) * SCH + c] = make_float2(m, sum);
    }
    __syncthreads();

    // pass B: each thread accumulates its 32-s half from registers
    float acc2[H] = {};
    #pragma unroll
    for (int s = 0; s < 32; s++) {
        const float4 pa = *(const float4*)(&sc[sh * 32 + s][0]);
        const float4 pb = *(const float4*)(&sc[sh * 32 + s][4]);
        acc2[0] += pa.x * xv[s]; acc2[1] += pa.y * xv[s];
        acc2[2] += pa.z * xv[s]; acc2[3] += pa.w * xv[s];
        acc2[4] += pb.x * xv[s]; acc2[5] += pb.y * xv[s];
        acc2[6] += pb.z * xv[s]; acc2[7] += pb.w * xv[s];
    }
    // combine halves through qkL (dead after pass A; 2 barriers since last read)
    {
        float* stage = qkL;                 // [H][256]
        if (sh == 1) {
            #pragma unroll
            for (int hh = 0; hh < H; hh++) stage[hh * 256 + tt] = acc2[hh];
        }
        __syncthreads();
        if (sh == 0) {
            #pragma unroll
            for (int hh = 0; hh < H; hh++)
                xwp[(((size_t)(b * H + hh)) * SCH + c) * D + tt]
                    = acc2[hh] + stage[hh * 256 + tt];
        }
    }
}

// ---- combine 16 chunks + Wv GEMV + bv + Wo GEMV -> atomicAdd(out).
// grid = B*H*4 = 1024 blocks (b, h, dv-quarter of 64), 256 thr. (R8 body)
__global__ void __launch_bounds__(256, 4) k_po(
        const float* __restrict__ xwp, const float2* __restrict__ mlbuf,
        const float* __restrict__ Wv, const float* __restrict__ bv,
        const float* __restrict__ Wo, float* __restrict__ out) {
    const int blk = blockIdx.x;
    const int dvq = blk & 3;                // dv-quarter (64 outputs of Wv)
    const int bh  = blk >> 2;
    const int b = bh >> 3, h = bh & 7;
    const int t = threadIdx.x;
    __shared__ float scaleL[SCH];
    __shared__ float xwL[D];
    __shared__ float pp[256];
    __shared__ float pooledL[64];

    if (t < SCH) {                          // wave-parallel M, L, scales (16 lanes)
        const float2 ml = mlbuf[((size_t)(b * H + h)) * SCH + t];
        float M = ml.x;
        #pragma unroll
        for (int msk = 1; msk < 16; msk <<= 1) M = fmaxf(M, __shfl_xor(M, msk));
        const float p = __expf(ml.x - M);
        float L = ml.y * p;
        #pragma unroll
        for (int msk = 1; msk < 16; msk <<= 1) L += __shfl_xor(L, msk);
        scaleL[t] = p / L;
    }
    __syncthreads();
    {                                       // combine 16 chunks: xw[d=t]
        const float* xp = xwp + ((size_t)(b * H + h)) * SCH * D + t;
        float acc = 0.f;
        #pragma unroll
        for (int cc = 0; cc < SCH; cc++)
            acc += xp[(size_t)cc * D] * scaleL[cc];
        xwL[t] = acc;
    }
    __syncthreads();
    {                                       // Wv GEMV (this dv-quarter), split-K x4
        const int kseg = t >> 6;
        const int dvl  = t & 63;
        const float* wp = Wv + (size_t)(kseg * 64) * (D * H) + h * D + dvq * 64 + dvl;
        float acc = 0.f;
        #pragma unroll 8
        for (int dd = 0; dd < 64; dd++)
            acc += xwL[kseg * 64 + dd] * wp[(size_t)dd * (D * H)];
        pp[t] = acc;
    }
    __syncthreads();
    if (t < 64)
        pooledL[t] = pp[t] + pp[t + 64] + pp[t + 128] + pp[t + 192]
                   + bv[h * D + dvq * 64 + t];
    __syncthreads();
    {                                       // Wo GEMV over this dv-quarter
        const float* wo = Wo + (size_t)(h * D + dvq * 64) * D + t;
        float acc = 0.f;
        #pragma unroll 8
        for (int dv = 0; dv < 64; dv++)
            acc += pooledL[dv] * wo[(size_t)dv * D];
        atomicAdd(out + (size_t)b * D + t, acc);
    }
}

extern "C" void kernel_launch(void* const* d_in, const int* in_sizes, int n_in,
                              void* d_out, int out_size, void* d_ws, size_t ws_size,
                              hipStream_t stream) {
    const float* x     = (const float*)d_in[0];
    const float* Wk    = (const float*)d_in[1];
    const float* Wv    = (const float*)d_in[3];
    const float* bv    = (const float*)d_in[4];
    const float* query = (const float*)d_in[5];
    const float* Wo    = (const float*)d_in[6];
    const float* bo    = (const float*)d_in[7];
    float* out = (float*)d_out;
    float* ws  = (float*)d_ws;

    float*  qk    = ws + OFF_QK;
    float2* mlbuf = (float2*)(ws + OFF_ML);
    float*  xwp   = ws + OFF_XWP;

    k_prep<<<dim3(H * 32), dim3(256), 0, stream>>>(Wk, query, bo, qk, out);
    k_fused<<<dim3(B * SCH), dim3(512), 0, stream>>>(x, qk, xwp, mlbuf);
    k_po<<<dim3(B * H * 4), dim3(256), 0, stream>>>(xwp, mlbuf, Wv, bv, Wo, out);
}

// Round 11
// 108.131 us; speedup vs baseline: 1.0256x; 1.0256x over previous
//
#include <hip/hip_runtime.h>

#define D 256
#define H 8
#define B 32
#define S 1024
#define SCH 16      // s-chunks per batch
#define SCS 64      // s per chunk  (best-measured stage-1 geometry)

// workspace layout (float offsets)
#define OFF_QK   0          // [H][D]                 2048
#define OFF_ML   2048       // [B][H][SCH] float2     8192 floats
#define OFF_XWP  10240      // [B][H][SCH][D]         1048576 floats (4 MB)

// ---- qk[h][k] = Wk[k, h*D+:] . q[h];  out = bo init. (R8-verified body)
__global__ void __launch_bounds__(256) k_prep(
        const float* __restrict__ Wk, const float* __restrict__ query,
        const float* __restrict__ bo, float* __restrict__ qk,
        float* __restrict__ out) {
    const int h  = blockIdx.x >> 5;
    const int kc = blockIdx.x & 31;
    const int t  = threadIdx.x;
    const int kl = t >> 5;
    const int dq = t & 31;
    const int k  = kc * 8 + kl;
    const int d0 = dq * 8;
    const float* wrow = Wk + (size_t)k * (D * H) + h * D + d0;
    const float* qrow = query + h * D + d0;
    const float4 w0 = *(const float4*)(wrow);
    const float4 w1 = *(const float4*)(wrow + 4);
    const float4 q0 = *(const float4*)(qrow);
    const float4 q1 = *(const float4*)(qrow + 4);
    float acc = w0.x * q0.x + w0.y * q0.y + w0.z * q0.z + w0.w * q0.w
              + w1.x * q1.x + w1.y * q1.y + w1.z * q1.z + w1.w * q1.w;
    #pragma unroll
    for (int msk = 1; msk < 32; msk <<= 1) acc += __shfl_xor(acc, msk);
    if (dq == 0) qk[h * D + k] = acc;
    if (h == 0) out[(size_t)kc * D + t] = bo[t];
}

// ---- One (b, chunk of 64 s): scores -> chunk softmax (m,l saved) ->
// unnormalized weighted sum. grid = B*SCH = 512 blocks, 256 thr.
// Pass-B x column prefetched into registers BEFORE the softmax phase
// (64 scalar loads in flight across both softmax barriers -> latency hidden).
__global__ void __launch_bounds__(256, 2) k_fused(
        const float* __restrict__ x, const float* __restrict__ qk,
        float* __restrict__ xwp, float2* __restrict__ mlbuf) {
    const int b  = blockIdx.x >> 4;
    const int c  = blockIdx.x & 15;
    const int s0 = c * SCS;
    const int t  = threadIdx.x;
    __shared__ float qkL[H * D];            // 8 KB
    __shared__ float sc[SCS][H];            // 2 KB
    {
        float4* q4 = (float4*)qkL;
        q4[t]       = ((const float4*)qk)[t];
        q4[t + 256] = ((const float4*)qk)[t + 256];
    }
    __syncthreads();

    // pass A: thread = (sl = t>>2: 64 s) x (dq = t&3: 64 d's).
    // XOR-staggered j: lanes dq=0..3 read qkL at distinct bank groups.
    {
        const int sl = t >> 2;
        const int dq = t & 3;
        const int d0 = dq * 64;
        const float* xrow = x + ((size_t)(b * S + s0 + sl)) * D + d0;
        float accA[H] = {};
        #pragma unroll
        for (int j0 = 0; j0 < 16; j0++) {
            const int j = (j0 + dq * 4) & 15;
            const float4 xv = *(const float4*)(xrow + j * 4);
            #pragma unroll
            for (int hh = 0; hh < H; hh++) {
                const float4 qv = *(const float4*)(&qkL[hh * D + d0 + j * 4]);
                accA[hh] += xv.x * qv.x + xv.y * qv.y + xv.z * qv.z + xv.w * qv.w;
            }
        }
        #pragma unroll
        for (int hh = 0; hh < H; hh++) {
            accA[hh] += __shfl_xor(accA[hh], 1);
            accA[hh] += __shfl_xor(accA[hh], 2);
        }
        if (dq == 0) {
            #pragma unroll
            for (int hh = 0; hh < H; hh++)
                sc[sl][hh] = accA[hh];
        }
    }

    // prefetch pass-B column x[.][t] into registers NOW: the 64 loads stay
    // in flight across the softmax barriers (softmax does no VMEM work).
    float xv[64];
    {
        const float* xp = x + ((size_t)(b * S + s0)) * D + t;
        #pragma unroll
        for (int s = 0; s < SCS; s++) xv[s] = xp[(size_t)s * D];
    }
    __syncthreads();

    // chunk softmax over 64 s per head: thread = (hh = t>>5) x (u = t&31)
    {
        const int hh = t >> 5;
        const int u  = t & 31;
        const float v0 = sc[u][hh], v1 = sc[u + 32][hh];
        float m = fmaxf(v0, v1);
        #pragma unroll
        for (int msk = 1; msk < 32; msk <<= 1) m = fmaxf(m, __shfl_xor(m, msk));
        const float e0 = __expf(v0 - m), e1 = __expf(v1 - m);
        float sum = e0 + e1;
        #pragma unroll
        for (int msk = 1; msk < 32; msk <<= 1) sum += __shfl_xor(sum, msk);
        sc[u][hh] = e0;
        sc[u + 32][hh] = e1;
        if (u == 0) mlbuf[((size_t)(b * H + hh)) * SCH + c] = make_float2(m, sum);
    }
    __syncthreads();

    // pass B: thread = d (t); x from registers, p broadcast from LDS.
    {
        float acc2[H] = {};
        #pragma unroll
        for (int s = 0; s < SCS; s++) {
            const float4 pa = *(const float4*)(&sc[s][0]);
            const float4 pb = *(const float4*)(&sc[s][4]);
            acc2[0] += pa.x * xv[s]; acc2[1] += pa.y * xv[s];
            acc2[2] += pa.z * xv[s]; acc2[3] += pa.w * xv[s];
            acc2[4] += pb.x * xv[s]; acc2[5] += pb.y * xv[s];
            acc2[6] += pb.z * xv[s]; acc2[7] += pb.w * xv[s];
        }
        #pragma unroll
        for (int hh = 0; hh < H; hh++)
            xwp[(((size_t)(b * H + hh)) * SCH + c) * D + t] = acc2[hh];
    }
}

// ---- combine 16 chunks + Wv GEMV + bv + Wo GEMV -> atomicAdd(out).
// grid = B*H*4 = 1024 blocks (b, h, dv-quarter of 64), 256 thr. (R8 body)
__global__ void __launch_bounds__(256, 4) k_po(
        const float* __restrict__ xwp, const float2* __restrict__ mlbuf,
        const float* __restrict__ Wv, const float* __restrict__ bv,
        const float* __restrict__ Wo, float* __restrict__ out) {
    const int blk = blockIdx.x;
    const int dvq = blk & 3;                // dv-quarter (64 outputs of Wv)
    const int bh  = blk >> 2;
    const int b = bh >> 3, h = bh & 7;
    const int t = threadIdx.x;
    __shared__ float scaleL[SCH];
    __shared__ float xwL[D];
    __shared__ float pp[256];
    __shared__ float pooledL[64];

    if (t < SCH) {                          // wave-parallel M, L, scales (16 lanes)
        const float2 ml = mlbuf[((size_t)(b * H + h)) * SCH + t];
        float M = ml.x;
        #pragma unroll
        for (int msk = 1; msk < 16; msk <<= 1) M = fmaxf(M, __shfl_xor(M, msk));
        const float p = __expf(ml.x - M);
        float L = ml.y * p;
        #pragma unroll
        for (int msk = 1; msk < 16; msk <<= 1) L += __shfl_xor(L, msk);
        scaleL[t] = p / L;
    }
    __syncthreads();
    {                                       // combine 16 chunks: xw[d=t]
        const float* xp = xwp + ((size_t)(b * H + h)) * SCH * D + t;
        float acc = 0.f;
        #pragma unroll
        for (int cc = 0; cc < SCH; cc++)
            acc += xp[(size_t)cc * D] * scaleL[cc];
        xwL[t] = acc;
    }
    __syncthreads();
    {                                       // Wv GEMV (this dv-quarter), split-K x4
        const int kseg = t >> 6;
        const int dvl  = t & 63;
        const float* wp = Wv + (size_t)(kseg * 64) * (D * H) + h * D + dvq * 64 + dvl;
        float acc = 0.f;
        #pragma unroll 8
        for (int dd = 0; dd < 64; dd++)
            acc += xwL[kseg * 64 + dd] * wp[(size_t)dd * (D * H)];
        pp[t] = acc;
    }
    __syncthreads();
    if (t < 64)
        pooledL[t] = pp[t] + pp[t + 64] + pp[t + 128] + pp[t + 192]
                   + bv[h * D + dvq * 64 + t];
    __syncthreads();
    {                                       // Wo GEMV over this dv-quarter
        const float* wo = Wo + (size_t)(h * D + dvq * 64) * D + t;
        float acc = 0.f;
        #pragma unroll 8
        for (int dv = 0; dv < 64; dv++)
            acc += pooledL[dv] * wo[(size_t)dv * D];
        atomicAdd(out + (size_t)b * D + t, acc);
    }
}

extern "C" void kernel_launch(void* const* d_in, const int* in_sizes, int n_in,
                              void* d_out, int out_size, void* d_ws, size_t ws_size,
                              hipStream_t stream) {
    const float* x     = (const float*)d_in[0];
    const float* Wk    = (const float*)d_in[1];
    const float* Wv    = (const float*)d_in[3];
    const float* bv    = (const float*)d_in[4];
    const float* query = (const float*)d_in[5];
    const float* Wo    = (const float*)d_in[6];
    const float* bo    = (const float*)d_in[7];
    float* out = (float*)d_out;
    float* ws  = (float*)d_ws;

    float*  qk    = ws + OFF_QK;
    float2* mlbuf = (float2*)(ws + OFF_ML);
    float*  xwp   = ws + OFF_XWP;

    k_prep<<<dim3(H * 32), dim3(256), 0, stream>>>(Wk, query, bo, qk, out);
    k_fused<<<dim3(B * SCH), dim3(256), 0, stream>>>(x, qk, xwp, mlbuf);
    k_po<<<dim3(B * H * 4), dim3(256), 0, stream>>>(xwp, mlbuf, Wv, bv, Wo, out);
}